// Round 11
// baseline (2495.093 us; speedup 1.0000x reference)
//
#include <hip/hip_runtime.h>
#include <cstdint>

typedef unsigned short u16;
typedef __attribute__((ext_vector_type(8))) short s8v;    // 8 x bf16
typedef __attribute__((ext_vector_type(4))) float f4v;
typedef __attribute__((ext_vector_type(16))) float f16v;  // 32x32 MFMA acc

#define TSEQ 200
#define HSLOT (256 * 512)

__device__ __forceinline__ u16 f2bf(float f) {
  uint32_t u = __float_as_uint(f);
  u += 0x7fffu + ((u >> 16) & 1u);
  return (u16)(u >> 16);
}
__device__ __forceinline__ float bf2f(u16 h) {
  return __uint_as_float(((uint32_t)h) << 16);
}
__device__ __forceinline__ float sigf(float x) { return 1.f / (1.f + __expf(-x)); }
__device__ __forceinline__ float tanhfast(float x) { return 2.f / (1.f + __expf(-2.f * x)) - 1.f; }

// Device-scope (LLC) H-path: sc1 only. Plain cached loads for X/weights (L2-resident).
// offset: must precede sc1 on gfx950.
__device__ __forceinline__ void ld_c(s8v& d, const u16* p, int ofs) {
  asm volatile("global_load_dwordx4 %0, %1, off offset:%2 sc1"
               : "=v"(d) : "v"(p), "n"(ofs));
}
__device__ __forceinline__ void ld_nc(s8v& d, const u16* p, int ofs) {
  asm volatile("global_load_dwordx4 %0, %1, off offset:%2"
               : "=v"(d) : "v"(p), "n"(ofs));
}
__device__ __forceinline__ void vmwait(int n) {
  asm volatile("s_waitcnt vmcnt(%0)" :: "n"(n) : "memory");
}
__device__ __forceinline__ void cstore_d(u16* p, uint32_t v) {
  asm volatile("global_store_dword %0, %1, off sc1" :: "v"(p), "v"(v) : "memory");
}

// ---------------- precompute ----------------

__global__ void zero_ws(uint32_t* p, int n) {
  int i = blockIdx.x * 256 + threadIdx.x;
  if (i < n) p[i] = 0u;
}

// X[t][b(256)][e(128)] bf16, zero-padded b>=250, e>=100
__global__ void gather_x(const int* __restrict__ tokens, const float* __restrict__ emb,
                         u16* __restrict__ X) {
  int idx = blockIdx.x * 256 + threadIdx.x;
  if (idx >= TSEQ * 256 * 16) return;
  int e0 = (idx & 15) * 8;
  int b  = (idx >> 4) & 255;
  int t  = idx >> 12;
  u16 v[8];
  if (b < 250) {
    int tok = tokens[b * TSEQ + t];
    const float* er = emb + (size_t)tok * 100;
#pragma unroll
    for (int j = 0; j < 8; ++j) {
      int e = e0 + j;
      v[j] = (e < 100) ? f2bf(er[e]) : (u16)0;
    }
  } else {
#pragma unroll
    for (int j = 0; j < 8; ++j) v[j] = 0;
  }
  *(s8v*)&X[(size_t)idx * 8] = *(const s8v*)v;
}

// Pack weights for 32x32x16 B-frags.
// layout [ub(32)][ks(nk16)][colt(2)][col(32)][kh(2)][e(8)] bf16.
// element k = ks*16+kh*8+e ; gate-col = (colt*2+(col>>4))*512 + ub*16 + (col&15)
__global__ void pack_wB(const float* __restrict__ A, const float* __restrict__ Bm,
                        u16* __restrict__ out, int nk16, int split, int arows) {
  int idx = blockIdx.x * 256 + threadIdx.x;
  int total = 32 * nk16 * 2 * 32 * 2;
  if (idx >= total) return;
  int kh = idx & 1;
  int col = (idx >> 1) & 31;
  int colt = (idx >> 6) & 1;
  int rest = idx >> 7;
  int ks = rest % nk16;
  int ub = rest / nk16;
  int gcol = (colt * 2 + (col >> 4)) * 512 + ub * 16 + (col & 15);
  u16 v[8];
#pragma unroll
  for (int e = 0; e < 8; ++e) {
    int k = ks * 16 + kh * 8 + e;
    float f;
    if (k < split) f = (k < arows) ? A[(size_t)k * 2048 + gcol] : 0.f;
    else           f = Bm[(size_t)(k - split) * 2048 + gcol];
    v[e] = f2bf(f);
  }
  *(s8v*)&out[(size_t)idx * 8] = *(const s8v*)v;
}

// ---------------- pipelined step GEMM ----------------
// A-panel (NS slots) issued ALL upfront: one LLC latency, not per-slot.
// B streamed from (XCD-local, L2-resident) packed weights with W=6 window.
// vmcnt queue: A[0..NS-1], then B pairs in slot order -> wait 2*min(W,rem).
template <int NS, int NX>
__device__ __forceinline__ void pipew(const u16* pX, const u16* pH, const u16* pB,
                                      f16v& acc0, f16v& acc1) {
  s8v a[NS];
#pragma unroll
  for (int s = 0; s < NS; ++s) {
    if (s < NX) ld_nc(a[s], pX, s * 32);
    else        ld_c(a[s], pH, (s - NX) * 32);
  }
  constexpr int W = NS < 6 ? NS : 6;
  s8v b0[NS], b1[NS];
#pragma unroll
  for (int j = 0; j < W; ++j) {
    ld_nc(b0[j], pB + j * 1024, 0);
    ld_nc(b1[j], pB + j * 1024, 1024);
  }
#pragma unroll
  for (int s = 0; s < NS; ++s) {
    const int j = s + W;
    if (j < NS) {
      ld_nc(b0[j], pB + j * 1024, 0);
      ld_nc(b1[j], pB + j * 1024, 1024);
    }
    const int rem = NS - 1 - s;
    vmwait(2 * (rem < W ? rem : W));    // A[s] retired long ago; B pair s done
    __builtin_amdgcn_sched_barrier(0);  // rule 18
    acc0 = __builtin_amdgcn_mfma_f32_32x32x16_bf16(a[s], b0[s], acc0, 0, 0, 0);
    acc1 = __builtin_amdgcn_mfma_f32_32x32x16_bf16(a[s], b1[s], acc1, 0, 0, 0);
  }
}

// ---------------- per-band wave-cooperative layer body ----------------
// Block = 32 rows (band) x 16 units (ub) x full K, K split over 4 waves.
// Cross-wave reduce via 32 KB LDS; h stored as packed dword (2 cells/thread).
template <bool LH, int NS, int NK16, int NX>
__device__ __forceinline__ void run_layer(int band, int ub, int w, int lane, int tid,
    const u16* __restrict__ Wp, const u16* __restrict__ X,
    u16* __restrict__ H0, u16* __restrict__ H1,
    const float* __restrict__ bp, unsigned* fL0b, unsigned* fL1b, float* rbuf) {
  const u16* pB = Wp + (size_t)(ub * NK16 + w * NS) * 1024
                     + ((lane & 31) * 2 + (lane >> 5)) * 8;
  const int arow = band * 32 + (lane & 31);
  const int kchE = (lane >> 5) * 8;
  const int u0 = (tid * 2) & 15;
  float bias0[4], bias1[4];
#pragma unroll
  for (int g = 0; g < 4; ++g) {
    bias0[g] = bp[g * 512 + ub * 16 + u0];
    bias1[g] = bp[g * 512 + ub * 16 + u0 + 1];
  }
  float c0 = 0.f, c1 = 0.f;
  // ---- per-wave poll target ----
  unsigned* pp; int tofs;
  if (LH) {
    if (w < 2) { pp = fL0b + (lane & 31); tofs = 1; }   // need h0[t]
    else       { pp = fL1b + (lane & 31); tofs = 0; }   // need h1[t-1]
  } else {
    pp = (lane < 32) ? (fL0b + lane) : (fL1b + (lane - 32));
    tofs = (lane < 32) ? 0 : -3;                        // h0[t-1] ; ring safety
  }
  unsigned* sigp = (LH ? fL1b : fL0b) + ub;

  for (int t = 0; t < TSEQ; ++t) {
    const int cs = t & 3, ps = (t + 3) & 3;
    {  // poll (band-local flags)
      const int thr = t + tofs;
      unsigned v;
      do {
        v = __hip_atomic_load(pp, __ATOMIC_RELAXED, __HIP_MEMORY_SCOPE_AGENT);
      } while (!__all((int)v >= thr));
    }
    // ---- A bases for this wave's k-slice ----
    const u16 *pH, *pX;
    if (LH) {
      pH = (w < 2 ? H0 + (size_t)cs * HSLOT : H1 + (size_t)ps * HSLOT)
           + (size_t)arow * 512 + kchE + (w & 1) * 256;
      pX = pH;
    } else if (NX > 0) {  // L0 wave 0: 8 X-slots + 2 h0-slots
      pX = X + (size_t)t * 32768 + arow * 128 + kchE;
      pH = H0 + (size_t)ps * HSLOT + (size_t)arow * 512 + kchE;
    } else {              // L0 waves 1-3: h0 slice
      pH = H0 + (size_t)ps * HSLOT + (size_t)arow * 512 + kchE + (w * 10 - 8) * 16;
      pX = pH;
    }
    f16v acc0 = {}, acc1 = {};
    pipew<NS, NX>(pX, pH, pB, acc0, acc1);
    // ---- raw partials -> LDS [w][colt][q][lane][4] ----
#pragma unroll
    for (int q = 0; q < 4; ++q) {
      f4v v0 = {acc0[4*q], acc0[4*q+1], acc0[4*q+2], acc0[4*q+3]};
      f4v v1 = {acc1[4*q], acc1[4*q+1], acc1[4*q+2], acc1[4*q+3]};
      *(f4v*)&rbuf[(w * 8 + q) * 256 + lane * 4] = v0;
      *(f4v*)&rbuf[(w * 8 + 4 + q) * 256 + lane * 4] = v1;
    }
    __syncthreads();
    // ---- epilogue: 2 adjacent cells/thread, sum 4 wave-partials, 1 dword store ----
    u16* Hout = (LH ? H1 : H0) + (size_t)cs * HSLOT;
    const int row = tid >> 3, u = (tid * 2) & 15;
    const int hi = (row >> 2) & 1, r = (row & 3) | ((row >> 3) << 2);
    u16 hv[2];
    float cc[2] = {c0, c1};
    const float* bb[2] = {bias0, bias1};
#pragma unroll
    for (int h = 0; h < 2; ++h) {
      float gs[4];
#pragma unroll
      for (int g = 0; g < 4; ++g) {
        const int dwb = ((g >> 1) * 4 + (r >> 2)) * 256
                        + (((g & 1) << 4) + (u + h) + (hi << 5)) * 4 + (r & 3);
        gs[g] = rbuf[dwb] + rbuf[dwb + 2048] + rbuf[dwb + 4096] + rbuf[dwb + 6144];
      }
      float cn = sigf(gs[1] + bb[h][1]) * cc[h] + sigf(gs[0] + bb[h][0]) * tanhfast(gs[2] + bb[h][2]);
      cc[h] = cn;
      hv[h] = f2bf(sigf(gs[3] + bb[h][3]) * tanhfast(cn));
    }
    c0 = cc[0]; c1 = cc[1];
    cstore_d(&Hout[(size_t)(band * 32 + row) * 512 + ub * 16 + u],
             (uint32_t)hv[0] | ((uint32_t)hv[1] << 16));
    vmwait(0);          // h at LLC
    __syncthreads();    // all threads' stores drained (also LDS WAR guard)
    if (tid == 0)
      __hip_atomic_store(sigp, (unsigned)(t + 1), __ATOMIC_RELAXED, __HIP_MEMORY_SCOPE_AGENT);
  }
}

__global__ void __launch_bounds__(256, 2)
lstm_main(const float* __restrict__ b0, const float* __restrict__ b1,
          const u16* __restrict__ W0p, const u16* __restrict__ W1p,
          const u16* __restrict__ X, u16* __restrict__ H0,
          u16* __restrict__ H1, unsigned* __restrict__ fL0,
          unsigned* __restrict__ fL1) {
  __shared__ float rbuf[8192];   // 32 KB raw-accumulator exchange
  const int tid = threadIdx.x, lane = tid & 63, w = tid >> 6;
  // XCD-aware mapping (blockIdx round-robins XCDs): each XCD owns 4 ub values for
  // both layers and all bands -> weight slices (832 KB/XCD) stay L2-resident.
  const int blk = blockIdx.x;
  const int xcd = blk & 7, q = blk >> 3;
  const int ub = xcd * 4 + (q & 3);
  const bool Lh = ((q >> 2) & 1) != 0;
  const int band = q >> 3;
  unsigned* fL0b = fL0 + band * 32;
  unsigned* fL1b = fL1 + band * 32;
  if (Lh)
    run_layer<true, 16, 64, 0>(band, ub, w, lane, tid, W1p, X, H0, H1, b1, fL0b, fL1b, rbuf);
  else if (w == 0)
    run_layer<false, 10, 40, 8>(band, ub, w, lane, tid, W0p, X, H0, H1, b0, fL0b, fL1b, rbuf);
  else
    run_layer<false, 10, 40, 0>(band, ub, w, lane, tid, W0p, X, H0, H1, b0, fL0b, fL1b, rbuf);
}

// ---------------- final dense (affine collapse) + sigmoid ----------------

__global__ void dense_out(const u16* __restrict__ H1f, const float* __restrict__ wd1,
                          const float* __restrict__ bd1, const float* __restrict__ wd2,
                          const float* __restrict__ bd2, float* __restrict__ out) {
  __shared__ float wv[512];
  __shared__ float beff;
  const int t = threadIdx.x;  // 512 threads
  {
    float s = 0.f;
#pragma unroll 4
    for (int j = 0; j < 32; ++j) s += wd1[t * 32 + j] * wd2[j];
    wv[t] = s;
  }
  if (t == 0) {
    float sb = 0.f;
    for (int j = 0; j < 32; ++j) sb += bd1[j] * wd2[j];
    beff = sb + bd2[0];
  }
  __syncthreads();
  if (t < 250) {
    const u16* hr = H1f + (size_t)t * 512;
    float acc = 0.f;
    for (int u = 0; u < 512; u += 8) {
      s8v hv = *(const s8v*)&hr[u];
#pragma unroll
      for (int j = 0; j < 8; ++j) acc += bf2f((u16)hv[j]) * wv[u + j];
    }
    out[t] = sigf(acc + beff);
  }
}

// ---------------- host ----------------

extern "C" void kernel_launch(void* const* d_in, const int* in_sizes, int n_in,
                              void* d_out, int out_size, void* d_ws, size_t ws_size,
                              hipStream_t stream) {
  const int*   tokens = (const int*)  d_in[0];
  const float* emb    = (const float*)d_in[1];
  const float* k0     = (const float*)d_in[2];
  const float* r0     = (const float*)d_in[3];
  const float* b0     = (const float*)d_in[4];
  const float* k1     = (const float*)d_in[5];
  const float* r1     = (const float*)d_in[6];
  const float* b1     = (const float*)d_in[7];
  const float* wd1    = (const float*)d_in[8];
  const float* bd1    = (const float*)d_in[9];
  const float* wd2    = (const float*)d_in[10];
  const float* bd2    = (const float*)d_in[11];
  float* out = (float*)d_out;

  char* ws = (char*)d_ws;
  // layout: fL0[8][32] @0 ; fL1 @2048 ; H0 ring 4x256KB @8192 ; H1 ring ;
  //         X 12.5MB ; W0p 2.5MB ; W1p 4MB
  unsigned* fL0 = (unsigned*)ws;
  unsigned* fL1 = (unsigned*)(ws + 2048);
  u16* H0  = (u16*)(ws + 8192);
  u16* H1  = (u16*)(ws + 8192 + 1048576);
  u16* X   = (u16*)(ws + 8192 + 2097152);
  u16* W0p = (u16*)(ws + 8192 + 2097152 + 13107200);
  u16* W1p = (u16*)(ws + 8192 + 2097152 + 13107200 + 2621440);

  zero_ws<<<2056, 256, 0, stream>>>((uint32_t*)ws, 526336);      // flags + H rings
  gather_x<<<3200, 256, 0, stream>>>(tokens, emb, X);
  pack_wB<<<640,  256, 0, stream>>>(k0, r0, W0p, 40, 128, 100);  // L0: K=128(pad)+512
  pack_wB<<<1024, 256, 0, stream>>>(k1, r1, W1p, 64, 512, 512);  // L1: K=512+512

  void* args[] = {(void*)&b0, (void*)&b1, (void*)&W0p, (void*)&W1p,
                  (void*)&X,  (void*)&H0, (void*)&H1, (void*)&fL0, (void*)&fL1};
  (void)hipLaunchCooperativeKernel(reinterpret_cast<void*>(lstm_main),
                                   dim3(512), dim3(256), args, 0, stream);

  dense_out<<<1, 512, 0, stream>>>(H1 + (size_t)3 * HSLOT, wd1, bd1, wd2, bd2, out);
}

// Round 12
// 2209.510 us; speedup vs baseline: 1.1293x; 1.1293x over previous
//
#include <hip/hip_runtime.h>
#include <cstdint>

typedef unsigned short u16;
typedef __attribute__((ext_vector_type(8))) short s8v;    // 8 x bf16
typedef __attribute__((ext_vector_type(4))) float f4v;
typedef __attribute__((ext_vector_type(16))) float f16v;  // 32x32 MFMA acc

#define TSEQ 200
#define HSLOT (256 * 512)

__device__ __forceinline__ u16 f2bf(float f) {
  uint32_t u = __float_as_uint(f);
  u += 0x7fffu + ((u >> 16) & 1u);
  return (u16)(u >> 16);
}
__device__ __forceinline__ float bf2f(u16 h) {
  return __uint_as_float(((uint32_t)h) << 16);
}
__device__ __forceinline__ float sigf(float x) { return 1.f / (1.f + __expf(-x)); }
__device__ __forceinline__ float tanhfast(float x) { return 2.f / (1.f + __expf(-2.f * x)) - 1.f; }

// Device-scope (LLC coherence point) H-path: sc1 only.
// offset: must precede sc1 on gfx950.
__device__ __forceinline__ void ld_c(s8v& d, const u16* p, int ofs) {
  asm volatile("global_load_dwordx4 %0, %1, off offset:%2 sc1"
               : "=v"(d) : "v"(p), "n"(ofs));
}
__device__ __forceinline__ void ld_nc(s8v& d, const u16* p, int ofs) {
  asm volatile("global_load_dwordx4 %0, %1, off offset:%2"
               : "=v"(d) : "v"(p), "n"(ofs));
}
// Plain cached load, asm-defined so the value cannot be rematerialized in-loop.
__device__ __forceinline__ s8v ld_b(const u16* p) {
  s8v d;
  asm volatile("global_load_dwordx4 %0, %1, off" : "=v"(d) : "v"(p));
  return d;
}
__device__ __forceinline__ void vmwait(int n) {
  asm volatile("s_waitcnt vmcnt(%0)" :: "n"(n) : "memory");
}
__device__ __forceinline__ void cstore(u16* p, u16 v) {
  asm volatile("global_store_short %0, %1, off sc1" :: "v"(p), "v"((uint32_t)v) : "memory");
}

// ---------------- precompute ----------------

__global__ void zero_ws(uint32_t* p, int n) {
  int i = blockIdx.x * 256 + threadIdx.x;
  if (i < n) p[i] = 0u;
}

// X[t][b(256)][e(128)] bf16, zero-padded b>=250, e>=100
__global__ void gather_x(const int* __restrict__ tokens, const float* __restrict__ emb,
                         u16* __restrict__ X) {
  int idx = blockIdx.x * 256 + threadIdx.x;
  if (idx >= TSEQ * 256 * 16) return;
  int e0 = (idx & 15) * 8;
  int b  = (idx >> 4) & 255;
  int t  = idx >> 12;
  u16 v[8];
  if (b < 250) {
    int tok = tokens[b * TSEQ + t];
    const float* er = emb + (size_t)tok * 100;
#pragma unroll
    for (int j = 0; j < 8; ++j) {
      int e = e0 + j;
      v[j] = (e < 100) ? f2bf(er[e]) : (u16)0;
    }
  } else {
#pragma unroll
    for (int j = 0; j < 8; ++j) v[j] = 0;
  }
  *(s8v*)&X[(size_t)idx * 8] = *(const s8v*)v;
}

// Pack weights for 32x32x16 B-frags.
// layout [ub(32)][ks(nk16)][colt(2)][col(32)][kh(2)][e(8)] bf16.
// element k = ks*16+kh*8+e ; gate-col = (colt*2+(col>>4))*512 + ub*16 + (col&15)
__global__ void pack_wB(const float* __restrict__ A, const float* __restrict__ Bm,
                        u16* __restrict__ out, int nk16, int split, int arows) {
  int idx = blockIdx.x * 256 + threadIdx.x;
  int total = 32 * nk16 * 2 * 32 * 2;
  if (idx >= total) return;
  int kh = idx & 1;
  int col = (idx >> 1) & 31;
  int colt = (idx >> 6) & 1;
  int rest = idx >> 7;
  int ks = rest % nk16;
  int ub = rest / nk16;
  int gcol = (colt * 2 + (col >> 4)) * 512 + ub * 16 + (col & 15);
  u16 v[8];
#pragma unroll
  for (int e = 0; e < 8; ++e) {
    int k = ks * 16 + kh * 8 + e;
    float f;
    if (k < split) f = (k < arows) ? A[(size_t)k * 2048 + gcol] : 0.f;
    else           f = Bm[(size_t)(k - split) * 2048 + gcol];
    v[e] = f2bf(f);
  }
  *(s8v*)&out[(size_t)idx * 8] = *(const s8v*)v;
}

// ---------------- per-band wave-cooperative layer body ----------------
// Block = 32 rows (band) x 16 units (ub) x full K, K split over 4 waves.
// B-frags asm-pinned in registers (partial spill tolerated). LDS cross-wave reduce.
template <bool LH, int NS, int NK16, int NX>
__device__ __forceinline__ void run_layer(int band, int ub, int w, int lane, int tid,
    const u16* __restrict__ Wp, const u16* __restrict__ X,
    u16* __restrict__ H0, u16* __restrict__ H1,
    const float* __restrict__ bp, unsigned* fL0b, unsigned* fL1b, float* rbuf) {
  // ---- persistent B registers (asm-defined: cannot be rematerialized) ----
  s8v B0[NS], B1[NS];
#pragma unroll
  for (int s = 0; s < NS; ++s) {
    const u16* bb = Wp + (size_t)(ub * NK16 + w * NS + s) * 1024
                       + ((lane & 31) * 2 + (lane >> 5)) * 8;
    B0[s] = ld_b(bb);
    B1[s] = ld_b(bb + 512);
  }
  vmwait(0);
  const int arow = band * 32 + (lane & 31);
  const int kchE = (lane >> 5) * 8;
  const int u0 = (tid * 2) & 15;
  float bias0[4], bias1[4];
#pragma unroll
  for (int g = 0; g < 4; ++g) {
    bias0[g] = bp[g * 512 + ub * 16 + u0];
    bias1[g] = bp[g * 512 + ub * 16 + u0 + 1];
  }
  float c0 = 0.f, c1 = 0.f;
  // ---- per-wave poll target ----
  unsigned* pp; int tofs;
  if (LH) {
    if (w < 2) { pp = fL0b + (lane & 31); tofs = 1; }   // need h0[t]
    else       { pp = fL1b + (lane & 31); tofs = 0; }   // need h1[t-1]
  } else {
    pp = (lane < 32) ? (fL0b + lane) : (fL1b + (lane - 32));
    tofs = (lane < 32) ? 0 : -7;                        // h0[t-1] ; ring safety (depth 8)
  }
  unsigned* sigp = (LH ? fL1b : fL0b) + ub;

  for (int t = 0; t < TSEQ; ++t) {
    const int cs = t & 7, ps = (t + 7) & 7;             // ring depth 8
    {  // poll (band-local flags; same-XCD producers)
      const int thr = t + tofs;
      unsigned v;
      do {
        v = __hip_atomic_load(pp, __ATOMIC_RELAXED, __HIP_MEMORY_SCOPE_AGENT);
      } while (!__all((int)v >= thr));
    }
    // ---- A bases for this wave's k-slice ----
    const u16 *pH, *pX;
    if (LH) {
      pH = (w < 2 ? H0 + (size_t)cs * HSLOT : H1 + (size_t)ps * HSLOT)
           + (size_t)arow * 512 + kchE + (w & 1) * 256;
      pX = pH;
    } else if (NX > 0) {  // L0 wave 0: 8 X-slots + 2 h0-slots
      pX = X + (size_t)t * 32768 + arow * 128 + kchE;
      pH = H0 + (size_t)ps * HSLOT + (size_t)arow * 512 + kchE;
    } else {              // L0 waves 1-3: h0 slice
      pH = H0 + (size_t)ps * HSLOT + (size_t)arow * 512 + kchE + (w * 10 - 8) * 16;
      pX = pH;
    }
    // ---- pipelined A loads + 32x32x16 MFMA (B in regs) ----
    f16v acc0 = {}, acc1 = {};
    s8v a[NS];
    constexpr int W = NS < 8 ? NS : 8;
#pragma unroll
    for (int s = 0; s < W; ++s) {
      if (s < NX) ld_nc(a[s], pX, s * 32); else ld_c(a[s], pH, s * 32);
    }
#pragma unroll
    for (int s = 0; s < NS; ++s) {
      const int j = s + W;
      if (j < NS) { if (j < NX) ld_nc(a[j], pX, j * 32); else ld_c(a[j], pH, j * 32); }
      const int rem = NS - 1 - s;
      vmwait(rem < W ? rem : W);
      __builtin_amdgcn_sched_barrier(0);  // rule 18
      acc0 = __builtin_amdgcn_mfma_f32_32x32x16_bf16(a[s], B0[s], acc0, 0, 0, 0);
      acc1 = __builtin_amdgcn_mfma_f32_32x32x16_bf16(a[s], B1[s], acc1, 0, 0, 0);
    }
    // ---- raw partials -> LDS [w][colt][q][lane][4] ----
#pragma unroll
    for (int q = 0; q < 4; ++q) {
      f4v v0 = {acc0[4*q], acc0[4*q+1], acc0[4*q+2], acc0[4*q+3]};
      f4v v1 = {acc1[4*q], acc1[4*q+1], acc1[4*q+2], acc1[4*q+3]};
      *(f4v*)&rbuf[(w * 8 + q) * 256 + lane * 4] = v0;
      *(f4v*)&rbuf[(w * 8 + 4 + q) * 256 + lane * 4] = v1;
    }
    __syncthreads();
    // ---- epilogue: 2 cells/thread, sum 4 wave-partials, gates -> c,h ----
    u16* Hout = (LH ? H1 : H0) + (size_t)cs * HSLOT;
    {
      const int cell = tid * 2, row = cell >> 4, u = cell & 15;
      const int hi = (row >> 2) & 1, r = (row & 3) | ((row >> 3) << 2);
      float gs[4];
#pragma unroll
      for (int g = 0; g < 4; ++g) {
        const int dwb = ((g >> 1) * 4 + (r >> 2)) * 256 + (((g & 1) << 4) + u + (hi << 5)) * 4 + (r & 3);
        gs[g] = rbuf[dwb] + rbuf[dwb + 2048] + rbuf[dwb + 4096] + rbuf[dwb + 6144];
      }
      float cn = sigf(gs[1] + bias0[1]) * c0 + sigf(gs[0] + bias0[0]) * tanhfast(gs[2] + bias0[2]);
      c0 = cn;
      cstore(&Hout[(size_t)(band * 32 + row) * 512 + ub * 16 + u],
             f2bf(sigf(gs[3] + bias0[3]) * tanhfast(cn)));
    }
    {
      const int cell = tid * 2 + 1, row = cell >> 4, u = cell & 15;
      const int hi = (row >> 2) & 1, r = (row & 3) | ((row >> 3) << 2);
      float gs[4];
#pragma unroll
      for (int g = 0; g < 4; ++g) {
        const int dwb = ((g >> 1) * 4 + (r >> 2)) * 256 + (((g & 1) << 4) + u + (hi << 5)) * 4 + (r & 3);
        gs[g] = rbuf[dwb] + rbuf[dwb + 2048] + rbuf[dwb + 4096] + rbuf[dwb + 6144];
      }
      float cn = sigf(gs[1] + bias1[1]) * c1 + sigf(gs[0] + bias1[0]) * tanhfast(gs[2] + bias1[2]);
      c1 = cn;
      cstore(&Hout[(size_t)(band * 32 + row) * 512 + ub * 16 + u],
             f2bf(sigf(gs[3] + bias1[3]) * tanhfast(cn)));
    }
    vmwait(0);          // h at LLC
    __syncthreads();    // all threads' stores drained (also LDS WAR guard)
    if (tid == 0)
      __hip_atomic_store(sigp, (unsigned)(t + 1), __ATOMIC_RELAXED, __HIP_MEMORY_SCOPE_AGENT);
  }
}

__global__ void __launch_bounds__(256, 2)
lstm_main(const float* __restrict__ b0, const float* __restrict__ b1,
          const u16* __restrict__ W0p, const u16* __restrict__ W1p,
          const u16* __restrict__ X, u16* __restrict__ H0,
          u16* __restrict__ H1, unsigned* __restrict__ fL0,
          unsigned* __restrict__ fL1) {
  __shared__ float rbuf[8192];   // 32 KB raw-accumulator exchange
  const int tid = threadIdx.x, lane = tid & 63, w = tid >> 6;
  // Band-per-XCD mapping: blockIdx round-robins XCDs (blk%8 = XCD), so putting
  // band = blk&7 co-locates a band's 64 blocks (both layers, all ubs) on ONE XCD.
  // All H/flag exchange becomes same-XCD; weights stream from LLC instead.
  const int blk = blockIdx.x;
  const int band = blk & 7;
  const int j = blk >> 3;              // 0..63
  const bool Lh = (j & 1) != 0;
  const int ub = j >> 1;               // 0..31
  unsigned* fL0b = fL0 + band * 32;
  unsigned* fL1b = fL1 + band * 32;
  if (Lh)
    run_layer<true, 16, 64, 0>(band, ub, w, lane, tid, W1p, X, H0, H1, b1, fL0b, fL1b, rbuf);
  else if (w == 0)
    run_layer<false, 10, 40, 8>(band, ub, w, lane, tid, W0p, X, H0, H1, b0, fL0b, fL1b, rbuf);
  else
    run_layer<false, 10, 40, 0>(band, ub, w, lane, tid, W0p, X, H0, H1, b0, fL0b, fL1b, rbuf);
}

// ---------------- final dense (affine collapse) + sigmoid ----------------

__global__ void dense_out(const u16* __restrict__ H1f, const float* __restrict__ wd1,
                          const float* __restrict__ bd1, const float* __restrict__ wd2,
                          const float* __restrict__ bd2, float* __restrict__ out) {
  __shared__ float wv[512];
  __shared__ float beff;
  const int t = threadIdx.x;  // 512 threads
  {
    float s = 0.f;
#pragma unroll 4
    for (int j = 0; j < 32; ++j) s += wd1[t * 32 + j] * wd2[j];
    wv[t] = s;
  }
  if (t == 0) {
    float sb = 0.f;
    for (int j = 0; j < 32; ++j) sb += bd1[j] * wd2[j];
    beff = sb + bd2[0];
  }
  __syncthreads();
  if (t < 250) {
    const u16* hr = H1f + (size_t)t * 512;
    float acc = 0.f;
    for (int u = 0; u < 512; u += 8) {
      s8v hv = *(const s8v*)&hr[u];
#pragma unroll
      for (int j = 0; j < 8; ++j) acc += bf2f((u16)hv[j]) * wv[u + j];
    }
    out[t] = sigf(acc + beff);
  }
}

// ---------------- host ----------------

extern "C" void kernel_launch(void* const* d_in, const int* in_sizes, int n_in,
                              void* d_out, int out_size, void* d_ws, size_t ws_size,
                              hipStream_t stream) {
  const int*   tokens = (const int*)  d_in[0];
  const float* emb    = (const float*)d_in[1];
  const float* k0     = (const float*)d_in[2];
  const float* r0     = (const float*)d_in[3];
  const float* b0     = (const float*)d_in[4];
  const float* k1     = (const float*)d_in[5];
  const float* r1     = (const float*)d_in[6];
  const float* b1     = (const float*)d_in[7];
  const float* wd1    = (const float*)d_in[8];
  const float* bd1    = (const float*)d_in[9];
  const float* wd2    = (const float*)d_in[10];
  const float* bd2    = (const float*)d_in[11];
  float* out = (float*)d_out;

  char* ws = (char*)d_ws;
  // layout: fL0[8][32] @0 ; fL1 @2048 ; H0 ring 8x256KB @8192 ; H1 ring 8x256KB ;
  //         X 12.5MB ; W0p 2.5MB ; W1p 4MB
  unsigned* fL0 = (unsigned*)ws;
  unsigned* fL1 = (unsigned*)(ws + 2048);
  u16* H0  = (u16*)(ws + 8192);
  u16* H1  = (u16*)(ws + 8192 + 2097152);
  u16* X   = (u16*)(ws + 8192 + 4194304);
  u16* W0p = (u16*)(ws + 8192 + 4194304 + 13107200);
  u16* W1p = (u16*)(ws + 8192 + 4194304 + 13107200 + 2621440);

  zero_ws<<<4104, 256, 0, stream>>>((uint32_t*)ws, 1050624);     // flags + H rings
  gather_x<<<3200, 256, 0, stream>>>(tokens, emb, X);
  pack_wB<<<640,  256, 0, stream>>>(k0, r0, W0p, 40, 128, 100);  // L0: K=128(pad)+512
  pack_wB<<<1024, 256, 0, stream>>>(k1, r1, W1p, 64, 512, 512);  // L1: K=512+512

  void* args[] = {(void*)&b0, (void*)&b1, (void*)&W0p, (void*)&W1p,
                  (void*)&X,  (void*)&H0, (void*)&H1, (void*)&fL0, (void*)&fL1};
  (void)hipLaunchCooperativeKernel(reinterpret_cast<void*>(lstm_main),
                                   dim3(512), dim3(256), args, 0, stream);

  dense_out<<<1, 512, 0, stream>>>(H1 + (size_t)7 * HSLOT, wd1, bd1, wd2, bd2, out);
}

// Round 15
// 2178.398 us; speedup vs baseline: 1.1454x; 1.0143x over previous
//
#include <hip/hip_runtime.h>
#include <cstdint>

typedef unsigned short u16;
typedef __attribute__((ext_vector_type(8))) short s8v;    // 8 x bf16
typedef __attribute__((ext_vector_type(4))) float f4v;
typedef __attribute__((ext_vector_type(16))) float f16v;  // 32x32 MFMA acc

#define TSEQ 200
#define HSLOT (256 * 512)

__device__ __forceinline__ u16 f2bf(float f) {
  uint32_t u = __float_as_uint(f);
  u += 0x7fffu + ((u >> 16) & 1u);
  return (u16)(u >> 16);
}
__device__ __forceinline__ float bf2f(u16 h) {
  return __uint_as_float(((uint32_t)h) << 16);
}
__device__ __forceinline__ float sigf(float x) { return 1.f / (1.f + __expf(-x)); }
__device__ __forceinline__ float tanhfast(float x) { return 2.f / (1.f + __expf(-2.f * x)) - 1.f; }

// Device-scope (LLC coherence point) H-path: sc1 only.
// offset: must precede sc1 on gfx950.
__device__ __forceinline__ void ld_c(s8v& d, const u16* p, int ofs) {
  asm volatile("global_load_dwordx4 %0, %1, off offset:%2 sc1"
               : "=v"(d) : "v"(p), "n"(ofs));
}
__device__ __forceinline__ void ld_nc(s8v& d, const u16* p, int ofs) {
  asm volatile("global_load_dwordx4 %0, %1, off offset:%2"
               : "=v"(d) : "v"(p), "n"(ofs));
}
// Plain cached load, asm-defined so the value cannot be rematerialized in-loop.
__device__ __forceinline__ s8v ld_b(const u16* p) {
  s8v d;
  asm volatile("global_load_dwordx4 %0, %1, off" : "=v"(d) : "v"(p));
  return d;
}
__device__ __forceinline__ void vmwait(int n) {
  asm volatile("s_waitcnt vmcnt(%0)" :: "n"(n) : "memory");
}
__device__ __forceinline__ void cstore(u16* p, u16 v) {
  asm volatile("global_store_short %0, %1, off sc1" :: "v"(p), "v"((uint32_t)v) : "memory");
}

// ---------------- precompute ----------------

__global__ void zero_ws(uint32_t* p, int n) {
  int i = blockIdx.x * 256 + threadIdx.x;
  if (i < n) p[i] = 0u;
}

// X[t][b(256)][e(128)] bf16, zero-padded b>=250, e>=100
__global__ void gather_x(const int* __restrict__ tokens, const float* __restrict__ emb,
                         u16* __restrict__ X) {
  int idx = blockIdx.x * 256 + threadIdx.x;
  if (idx >= TSEQ * 256 * 16) return;
  int e0 = (idx & 15) * 8;
  int b  = (idx >> 4) & 255;
  int t  = idx >> 12;
  u16 v[8];
  if (b < 250) {
    int tok = tokens[b * TSEQ + t];
    const float* er = emb + (size_t)tok * 100;
#pragma unroll
    for (int j = 0; j < 8; ++j) {
      int e = e0 + j;
      v[j] = (e < 100) ? f2bf(er[e]) : (u16)0;
    }
  } else {
#pragma unroll
    for (int j = 0; j < 8; ++j) v[j] = 0;
  }
  *(s8v*)&X[(size_t)idx * 8] = *(const s8v*)v;
}

// Pack weights for 32x32x16 B-frags.
// layout [ub(32)][ks(nk16)][colt(2)][col(32)][kh(2)][e(8)] bf16.
// element k = ks*16+kh*8+e ; gate-col = (colt*2+(col>>4))*512 + ub*16 + (col&15)
__global__ void pack_wB(const float* __restrict__ A, const float* __restrict__ Bm,
                        u16* __restrict__ out, int nk16, int split, int arows) {
  int idx = blockIdx.x * 256 + threadIdx.x;
  int total = 32 * nk16 * 2 * 32 * 2;
  if (idx >= total) return;
  int kh = idx & 1;
  int col = (idx >> 1) & 31;
  int colt = (idx >> 6) & 1;
  int rest = idx >> 7;
  int ks = rest % nk16;
  int ub = rest / nk16;
  int gcol = (colt * 2 + (col >> 4)) * 512 + ub * 16 + (col & 15);
  u16 v[8];
#pragma unroll
  for (int e = 0; e < 8; ++e) {
    int k = ks * 16 + kh * 8 + e;
    float f;
    if (k < split) f = (k < arows) ? A[(size_t)k * 2048 + gcol] : 0.f;
    else           f = Bm[(size_t)(k - split) * 2048 + gcol];
    v[e] = f2bf(f);
  }
  *(s8v*)&out[(size_t)idx * 8] = *(const s8v*)v;
}

// ---------------- per-band wave-cooperative layer body ----------------
// Block = 32 rows (band) x 16 units (ub) x full K, K split over 4 waves.
// B-frags asm-pinned in registers. LDS cross-wave reduce. Flags: agent-scope
// atomic load polls ONLY (anything weaker can be served by stale L1 -> hang,
// proven R13/R14).
template <bool LH, int NS, int NK16, int NX>
__device__ __forceinline__ void run_layer(int band, int ub, int w, int lane, int tid,
    const u16* __restrict__ Wp, const u16* __restrict__ X,
    u16* __restrict__ H0, u16* __restrict__ H1,
    const float* __restrict__ bp, unsigned* fL0b, unsigned* fL1b, float* rbuf) {
  // ---- persistent B registers (asm-defined: cannot be rematerialized) ----
  s8v B0[NS], B1[NS];
#pragma unroll
  for (int s = 0; s < NS; ++s) {
    const u16* bb = Wp + (size_t)(ub * NK16 + w * NS + s) * 1024
                       + ((lane & 31) * 2 + (lane >> 5)) * 8;
    B0[s] = ld_b(bb);
    B1[s] = ld_b(bb + 512);
  }
  vmwait(0);
  const int arow = band * 32 + (lane & 31);
  const int kchE = (lane >> 5) * 8;
  const int u0 = (tid * 2) & 15;
  float bias0[4], bias1[4];
#pragma unroll
  for (int g = 0; g < 4; ++g) {
    bias0[g] = bp[g * 512 + ub * 16 + u0];
    bias1[g] = bp[g * 512 + ub * 16 + u0 + 1];
  }
  float c0 = 0.f, c1 = 0.f;
  // ---- per-wave poll target ----
  unsigned* pp; int tofs;
  if (LH) {
    if (w < 2) { pp = fL0b + (lane & 31); tofs = 1; }   // need h0[t]
    else       { pp = fL1b + (lane & 31); tofs = 0; }   // need h1[t-1]
  } else {
    pp = (lane < 32) ? (fL0b + lane) : (fL1b + (lane - 32));
    tofs = (lane < 32) ? 0 : -7;                        // h0[t-1] ; ring safety (depth 8)
  }
  unsigned* sigp = (LH ? fL1b : fL0b) + ub;

  for (int t = 0; t < TSEQ; ++t) {
    const int cs = t & 7, ps = (t + 7) & 7;             // ring depth 8
    {  // poll (band-local flags; agent-scope = liveness-safe)
      const int thr = t + tofs;
      unsigned v;
      do {
        v = __hip_atomic_load(pp, __ATOMIC_RELAXED, __HIP_MEMORY_SCOPE_AGENT);
      } while (!__all((int)v >= thr));
    }
    // ---- A bases for this wave's k-slice ----
    const u16 *pH, *pX;
    if (LH) {
      pH = (w < 2 ? H0 + (size_t)cs * HSLOT : H1 + (size_t)ps * HSLOT)
           + (size_t)arow * 512 + kchE + (w & 1) * 256;
      pX = pH;
    } else if (NX > 0) {  // L0 wave 0: 8 X-slots + 2 h0-slots
      pX = X + (size_t)t * 32768 + arow * 128 + kchE;
      pH = H0 + (size_t)ps * HSLOT + (size_t)arow * 512 + kchE;
    } else {              // L0 waves 1-3: h0 slice
      pH = H0 + (size_t)ps * HSLOT + (size_t)arow * 512 + kchE + (w * 10 - 8) * 16;
      pX = pH;
    }
    // ---- pipelined A loads + 32x32x16 MFMA (B in regs) ----
    f16v acc0 = {}, acc1 = {};
    s8v a[NS];
    constexpr int W = NS < 8 ? NS : 8;
#pragma unroll
    for (int s = 0; s < W; ++s) {
      if (s < NX) ld_nc(a[s], pX, s * 32); else ld_c(a[s], pH, s * 32);
    }
#pragma unroll
    for (int s = 0; s < NS; ++s) {
      const int j = s + W;
      if (j < NS) { if (j < NX) ld_nc(a[j], pX, j * 32); else ld_c(a[j], pH, j * 32); }
      const int rem = NS - 1 - s;
      vmwait(rem < W ? rem : W);
      __builtin_amdgcn_sched_barrier(0);  // rule 18
      acc0 = __builtin_amdgcn_mfma_f32_32x32x16_bf16(a[s], B0[s], acc0, 0, 0, 0);
      acc1 = __builtin_amdgcn_mfma_f32_32x32x16_bf16(a[s], B1[s], acc1, 0, 0, 0);
    }
    // ---- raw partials -> LDS [w][colt][q][lane][4] ----
#pragma unroll
    for (int q = 0; q < 4; ++q) {
      f4v v0 = {acc0[4*q], acc0[4*q+1], acc0[4*q+2], acc0[4*q+3]};
      f4v v1 = {acc1[4*q], acc1[4*q+1], acc1[4*q+2], acc1[4*q+3]};
      *(f4v*)&rbuf[(w * 8 + q) * 256 + lane * 4] = v0;
      *(f4v*)&rbuf[(w * 8 + 4 + q) * 256 + lane * 4] = v1;
    }
    __syncthreads();
    // ---- epilogue: 2 cells/thread, sum 4 wave-partials, gates -> c,h ----
    u16* Hout = (LH ? H1 : H0) + (size_t)cs * HSLOT;
    {
      const int cell = tid * 2, row = cell >> 4, u = cell & 15;
      const int hi = (row >> 2) & 1, r = (row & 3) | ((row >> 3) << 2);
      float gs[4];
#pragma unroll
      for (int g = 0; g < 4; ++g) {
        const int dwb = ((g >> 1) * 4 + (r >> 2)) * 256 + (((g & 1) << 4) + u + (hi << 5)) * 4 + (r & 3);
        gs[g] = rbuf[dwb] + rbuf[dwb + 2048] + rbuf[dwb + 4096] + rbuf[dwb + 6144];
      }
      float cn = sigf(gs[1] + bias0[1]) * c0 + sigf(gs[0] + bias0[0]) * tanhfast(gs[2] + bias0[2]);
      c0 = cn;
      cstore(&Hout[(size_t)(band * 32 + row) * 512 + ub * 16 + u],
             f2bf(sigf(gs[3] + bias0[3]) * tanhfast(cn)));
    }
    {
      const int cell = tid * 2 + 1, row = cell >> 4, u = cell & 15;
      const int hi = (row >> 2) & 1, r = (row & 3) | ((row >> 3) << 2);
      float gs[4];
#pragma unroll
      for (int g = 0; g < 4; ++g) {
        const int dwb = ((g >> 1) * 4 + (r >> 2)) * 256 + (((g & 1) << 4) + u + (hi << 5)) * 4 + (r & 3);
        gs[g] = rbuf[dwb] + rbuf[dwb + 2048] + rbuf[dwb + 4096] + rbuf[dwb + 6144];
      }
      float cn = sigf(gs[1] + bias1[1]) * c1 + sigf(gs[0] + bias1[0]) * tanhfast(gs[2] + bias1[2]);
      c1 = cn;
      cstore(&Hout[(size_t)(band * 32 + row) * 512 + ub * 16 + u],
             f2bf(sigf(gs[3] + bias1[3]) * tanhfast(cn)));
    }
    vmwait(0);          // h ack'd at LLC before flag
    __syncthreads();    // all threads' stores drained (also LDS WAR guard)
    if (tid == 0)
      __hip_atomic_store(sigp, (unsigned)(t + 1), __ATOMIC_RELAXED, __HIP_MEMORY_SCOPE_AGENT);
  }
}

__global__ void __launch_bounds__(256, 2)
lstm_main(const float* __restrict__ b0, const float* __restrict__ b1,
          const u16* __restrict__ W0p, const u16* __restrict__ W1p,
          const u16* __restrict__ X, u16* __restrict__ H0,
          u16* __restrict__ H1, unsigned* __restrict__ fL0,
          unsigned* __restrict__ fL1) {
  __shared__ float rbuf[8192];   // 32 KB raw-accumulator exchange
  const int tid = threadIdx.x, lane = tid & 63, w = tid >> 6;
  // Balanced band-per-XCD mapping: band = sub&7 keeps a band's blocks on one XCD
  // (locality: R12 cut FETCH 478->90MB), and Lh = blk>=256 makes CU pair
  // (c, c+256) = L0+L1 of the same band/ub (no double-heavy straggler CUs).
  const int blk = blockIdx.x;
  const bool Lh = blk >= 256;
  const int sub = blk & 255;
  const int band = sub & 7;
  const int ub = sub >> 3;
  unsigned* fL0b = fL0 + band * 32;
  unsigned* fL1b = fL1 + band * 32;
  if (Lh)
    run_layer<true, 16, 64, 0>(band, ub, w, lane, tid, W1p, X, H0, H1, b1, fL0b, fL1b, rbuf);
  else if (w == 0)
    run_layer<false, 10, 40, 8>(band, ub, w, lane, tid, W0p, X, H0, H1, b0, fL0b, fL1b, rbuf);
  else
    run_layer<false, 10, 40, 0>(band, ub, w, lane, tid, W0p, X, H0, H1, b0, fL0b, fL1b, rbuf);
}

// ---------------- final dense (affine collapse) + sigmoid ----------------

__global__ void dense_out(const u16* __restrict__ H1f, const float* __restrict__ wd1,
                          const float* __restrict__ bd1, const float* __restrict__ wd2,
                          const float* __restrict__ bd2, float* __restrict__ out) {
  __shared__ float wv[512];
  __shared__ float beff;
  const int t = threadIdx.x;  // 512 threads
  {
    float s = 0.f;
#pragma unroll 4
    for (int j = 0; j < 32; ++j) s += wd1[t * 32 + j] * wd2[j];
    wv[t] = s;
  }
  if (t == 0) {
    float sb = 0.f;
    for (int j = 0; j < 32; ++j) sb += bd1[j] * wd2[j];
    beff = sb + bd2[0];
  }
  __syncthreads();
  if (t < 250) {
    const u16* hr = H1f + (size_t)t * 512;
    float acc = 0.f;
    for (int u = 0; u < 512; u += 8) {
      s8v hv = *(const s8v*)&hr[u];
#pragma unroll
      for (int j = 0; j < 8; ++j) acc += bf2f((u16)hv[j]) * wv[u + j];
    }
    out[t] = sigf(acc + beff);
  }
}

// ---------------- host ----------------

extern "C" void kernel_launch(void* const* d_in, const int* in_sizes, int n_in,
                              void* d_out, int out_size, void* d_ws, size_t ws_size,
                              hipStream_t stream) {
  const int*   tokens = (const int*)  d_in[0];
  const float* emb    = (const float*)d_in[1];
  const float* k0     = (const float*)d_in[2];
  const float* r0     = (const float*)d_in[3];
  const float* b0     = (const float*)d_in[4];
  const float* k1     = (const float*)d_in[5];
  const float* r1     = (const float*)d_in[6];
  const float* b1     = (const float*)d_in[7];
  const float* wd1    = (const float*)d_in[8];
  const float* bd1    = (const float*)d_in[9];
  const float* wd2    = (const float*)d_in[10];
  const float* bd2    = (const float*)d_in[11];
  float* out = (float*)d_out;

  char* ws = (char*)d_ws;
  // layout: fL0[8][32] @0 ; fL1 @2048 ; H0 ring 8x256KB @8192 ; H1 ring 8x256KB ;
  //         X 12.5MB ; W0p 2.5MB ; W1p 4MB
  unsigned* fL0 = (unsigned*)ws;
  unsigned* fL1 = (unsigned*)(ws + 2048);
  u16* H0  = (u16*)(ws + 8192);
  u16* H1  = (u16*)(ws + 8192 + 2097152);
  u16* X   = (u16*)(ws + 8192 + 4194304);
  u16* W0p = (u16*)(ws + 8192 + 4194304 + 13107200);
  u16* W1p = (u16*)(ws + 8192 + 4194304 + 13107200 + 2621440);

  zero_ws<<<4104, 256, 0, stream>>>((uint32_t*)ws, 1050624);     // flags + H rings
  gather_x<<<3200, 256, 0, stream>>>(tokens, emb, X);
  pack_wB<<<640,  256, 0, stream>>>(k0, r0, W0p, 40, 128, 100);  // L0: K=128(pad)+512
  pack_wB<<<1024, 256, 0, stream>>>(k1, r1, W1p, 64, 512, 512);  // L1: K=512+512

  void* args[] = {(void*)&b0, (void*)&b1, (void*)&W0p, (void*)&W1p,
                  (void*)&X,  (void*)&H0, (void*)&H1, (void*)&fL0, (void*)&fL1};
  (void)hipLaunchCooperativeKernel(reinterpret_cast<void*>(lstm_main),
                                   dim3(512), dim3(256), args, 0, stream);

  dense_out<<<1, 512, 0, stream>>>(H1 + (size_t)7 * HSLOT, wd1, bd1, wd2, bd2, out);
}

// Round 16
// 1744.390 us; speedup vs baseline: 1.4304x; 1.2488x over previous
//
#include <hip/hip_runtime.h>
#include <cstdint>

typedef unsigned short u16;
typedef __attribute__((ext_vector_type(8))) short s8v;    // 8 x bf16
typedef __attribute__((ext_vector_type(4))) float f4v;
typedef __attribute__((ext_vector_type(16))) float f16v;  // 32x32 MFMA acc

#define TSEQ 200
#define HSLOT (256 * 512)

__device__ __forceinline__ u16 f2bf(float f) {
  uint32_t u = __float_as_uint(f);
  u += 0x7fffu + ((u >> 16) & 1u);
  return (u16)(u >> 16);
}
__device__ __forceinline__ float bf2f(u16 h) {
  return __uint_as_float(((uint32_t)h) << 16);
}
__device__ __forceinline__ float sigf(float x) { return 1.f / (1.f + __expf(-x)); }
__device__ __forceinline__ float tanhfast(float x) { return 2.f / (1.f + __expf(-2.f * x)) - 1.f; }

// Device-scope (LLC) H-path: sc1. offset: must precede sc1 on gfx950.
__device__ __forceinline__ void ld_c(s8v& d, const u16* p, int ofs) {
  asm volatile("global_load_dwordx4 %0, %1, off offset:%2 sc1"
               : "=v"(d) : "v"(p), "n"(ofs));
}
__device__ __forceinline__ void ld_nc(s8v& d, const u16* p, int ofs) {
  asm volatile("global_load_dwordx4 %0, %1, off offset:%2"
               : "=v"(d) : "v"(p), "n"(ofs));
}
// Plain cached load, asm-defined so the value cannot be rematerialized in-loop.
__device__ __forceinline__ s8v ld_b(const u16* p) {
  s8v d;
  asm volatile("global_load_dwordx4 %0, %1, off" : "=v"(d) : "v"(p));
  return d;
}
__device__ __forceinline__ void vmwait(int n) {
  asm volatile("s_waitcnt vmcnt(%0)" :: "n"(n) : "memory");
}
__device__ __forceinline__ void cstore_d(u16* p, uint32_t v) {
  asm volatile("global_store_dword %0, %1, off sc1" :: "v"(p), "v"(v) : "memory");
}

// ---------------- precompute ----------------

__global__ void zero_ws(uint32_t* p, int n) {
  int i = blockIdx.x * 256 + threadIdx.x;
  if (i < n) p[i] = 0u;
}

// X[t][b(256)][e(128)] bf16, zero-padded b>=250, e>=100
__global__ void gather_x(const int* __restrict__ tokens, const float* __restrict__ emb,
                         u16* __restrict__ X) {
  int idx = blockIdx.x * 256 + threadIdx.x;
  if (idx >= TSEQ * 256 * 16) return;
  int e0 = (idx & 15) * 8;
  int b  = (idx >> 4) & 255;
  int t  = idx >> 12;
  u16 v[8];
  if (b < 250) {
    int tok = tokens[b * TSEQ + t];
    const float* er = emb + (size_t)tok * 100;
#pragma unroll
    for (int j = 0; j < 8; ++j) {
      int e = e0 + j;
      v[j] = (e < 100) ? f2bf(er[e]) : (u16)0;
    }
  } else {
#pragma unroll
    for (int j = 0; j < 8; ++j) v[j] = 0;
  }
  *(s8v*)&X[(size_t)idx * 8] = *(const s8v*)v;
}

// Pack weights for 32x32x16 B-frags.
// layout [ub(32)][ks(nk16)][colt(2)][col(32)][kh(2)][e(8)] bf16.
// element k = ks*16+kh*8+e ; gate-col = (colt*2+(col>>4))*512 + ub*16 + (col&15)
__global__ void pack_wB(const float* __restrict__ A, const float* __restrict__ Bm,
                        u16* __restrict__ out, int nk16, int split, int arows) {
  int idx = blockIdx.x * 256 + threadIdx.x;
  int total = 32 * nk16 * 2 * 32 * 2;
  if (idx >= total) return;
  int kh = idx & 1;
  int col = (idx >> 1) & 31;
  int colt = (idx >> 6) & 1;
  int rest = idx >> 7;
  int ks = rest % nk16;
  int ub = rest / nk16;
  int gcol = (colt * 2 + (col >> 4)) * 512 + ub * 16 + (col & 15);
  u16 v[8];
#pragma unroll
  for (int e = 0; e < 8; ++e) {
    int k = ks * 16 + kh * 8 + e;
    float f;
    if (k < split) f = (k < arows) ? A[(size_t)k * 2048 + gcol] : 0.f;
    else           f = Bm[(size_t)(k - split) * 2048 + gcol];
    v[e] = f2bf(f);
  }
  *(s8v*)&out[(size_t)idx * 8] = *(const s8v*)v;
}

// ---------------- per-band wave-cooperative layer body ----------------
// Block = 32 rows (band) x 16 units (ub) x full K, K split over 4 waves.
// B-frags asm-pinned in registers. LDS cross-wave reduce. Agent-scope flag
// polls only (weaker scopes hang on stale L1 — proven R13/R14). Poll spins at
// prio 0 with s_sleep so co-resident computing blocks keep the SIMD issue BW.
template <bool LH, int NS, int NK16, int NX>
__device__ __forceinline__ void run_layer(int band, int ub, int w, int lane, int tid,
    const u16* __restrict__ Wp, const u16* __restrict__ X,
    u16* __restrict__ H0, u16* __restrict__ H1,
    const float* __restrict__ bp, unsigned* fL0b, unsigned* fL1b, float* rbuf) {
  // ---- persistent B registers (asm-defined: cannot be rematerialized) ----
  s8v B0[NS], B1[NS];
#pragma unroll
  for (int s = 0; s < NS; ++s) {
    const u16* bb = Wp + (size_t)(ub * NK16 + w * NS + s) * 1024
                       + ((lane & 31) * 2 + (lane >> 5)) * 8;
    B0[s] = ld_b(bb);
    B1[s] = ld_b(bb + 512);
  }
  vmwait(0);
  const int arow = band * 32 + (lane & 31);
  const int kchE = (lane >> 5) * 8;
  const int u0 = (tid * 2) & 15;
  float bias0[4], bias1[4];
#pragma unroll
  for (int g = 0; g < 4; ++g) {
    bias0[g] = bp[g * 512 + ub * 16 + u0];
    bias1[g] = bp[g * 512 + ub * 16 + u0 + 1];
  }
  float c0 = 0.f, c1 = 0.f;
  // ---- per-wave poll target ----
  unsigned* pp; int tofs;
  if (LH) {
    if (w < 2) { pp = fL0b + (lane & 31); tofs = 1; }   // need h0[t]
    else       { pp = fL1b + (lane & 31); tofs = 0; }   // need h1[t-1]
  } else {
    pp = (lane < 32) ? (fL0b + lane) : (fL1b + (lane - 32));
    tofs = (lane < 32) ? 0 : -7;                        // h0[t-1] ; ring safety (depth 8)
  }
  unsigned* sigp = (LH ? fL1b : fL0b) + ub;

  for (int t = 0; t < TSEQ; ++t) {
    const int cs = t & 7, ps = (t + 7) & 7;             // ring depth 8
    {  // poll at low prio, sleeping between tries (don't steal partner's issue BW)
      const int thr = t + tofs;
      __builtin_amdgcn_s_setprio(0);
      for (;;) {
        unsigned v = __hip_atomic_load(pp, __ATOMIC_RELAXED, __HIP_MEMORY_SCOPE_AGENT);
        if (__all((int)v >= thr)) break;
        __builtin_amdgcn_s_sleep(1);
      }
      __builtin_amdgcn_s_setprio(1);
    }
    // ---- A bases for this wave's k-slice ----
    const u16 *pH, *pX;
    if (LH) {
      pH = (w < 2 ? H0 + (size_t)cs * HSLOT : H1 + (size_t)ps * HSLOT)
           + (size_t)arow * 512 + kchE + (w & 1) * 256;
      pX = pH;
    } else if (NX > 0) {  // L0 wave 0: 8 X-slots + 2 h0-slots
      pX = X + (size_t)t * 32768 + arow * 128 + kchE;
      pH = H0 + (size_t)ps * HSLOT + (size_t)arow * 512 + kchE;
    } else {              // L0 waves 1-3: h0 slice
      pH = H0 + (size_t)ps * HSLOT + (size_t)arow * 512 + kchE + (w * 10 - 8) * 16;
      pX = pH;
    }
    // ---- pipelined A loads + 32x32x16 MFMA (B in regs) ----
    f16v acc0 = {}, acc1 = {};
    s8v a[NS];
    constexpr int W = NS < 8 ? NS : 8;
#pragma unroll
    for (int s = 0; s < W; ++s) {
      if (s < NX) ld_nc(a[s], pX, s * 32); else ld_c(a[s], pH, s * 32);
    }
#pragma unroll
    for (int s = 0; s < NS; ++s) {
      const int j = s + W;
      if (j < NS) { if (j < NX) ld_nc(a[j], pX, j * 32); else ld_c(a[j], pH, j * 32); }
      const int rem = NS - 1 - s;
      vmwait(rem < W ? rem : W);
      __builtin_amdgcn_sched_barrier(0);  // rule 18
      acc0 = __builtin_amdgcn_mfma_f32_32x32x16_bf16(a[s], B0[s], acc0, 0, 0, 0);
      acc1 = __builtin_amdgcn_mfma_f32_32x32x16_bf16(a[s], B1[s], acc1, 0, 0, 0);
    }
    // ---- raw partials -> LDS [w][colt][q][lane][4] ----
#pragma unroll
    for (int q = 0; q < 4; ++q) {
      f4v v0 = {acc0[4*q], acc0[4*q+1], acc0[4*q+2], acc0[4*q+3]};
      f4v v1 = {acc1[4*q], acc1[4*q+1], acc1[4*q+2], acc1[4*q+3]};
      *(f4v*)&rbuf[(w * 8 + q) * 256 + lane * 4] = v0;
      *(f4v*)&rbuf[(w * 8 + 4 + q) * 256 + lane * 4] = v1;
    }
    __syncthreads();
    // ---- epilogue: 2 adjacent cells/thread, sum 4 wave-partials, 1 dword store ----
    u16* Hout = (LH ? H1 : H0) + (size_t)cs * HSLOT;
    const int row = tid >> 3, u = (tid * 2) & 15;
    const int hi = (row >> 2) & 1, r = (row & 3) | ((row >> 3) << 2);
    u16 hv[2];
    float cc[2] = {c0, c1};
    const float* bb[2] = {bias0, bias1};
#pragma unroll
    for (int h = 0; h < 2; ++h) {
      float gs[4];
#pragma unroll
      for (int g = 0; g < 4; ++g) {
        const int dwb = ((g >> 1) * 4 + (r >> 2)) * 256
                        + (((g & 1) << 4) + (u + h) + (hi << 5)) * 4 + (r & 3);
        gs[g] = rbuf[dwb] + rbuf[dwb + 2048] + rbuf[dwb + 4096] + rbuf[dwb + 6144];
      }
      float cn = sigf(gs[1] + bb[h][1]) * cc[h] + sigf(gs[0] + bb[h][0]) * tanhfast(gs[2] + bb[h][2]);
      cc[h] = cn;
      hv[h] = f2bf(sigf(gs[3] + bb[h][3]) * tanhfast(cn));
    }
    c0 = cc[0]; c1 = cc[1];
    cstore_d(&Hout[(size_t)(band * 32 + row) * 512 + ub * 16 + u],
             (uint32_t)hv[0] | ((uint32_t)hv[1] << 16));
    vmwait(0);          // h ack'd at LLC before flag
    __syncthreads();    // all threads' stores drained (also LDS WAR guard)
    if (tid == 0)
      __hip_atomic_store(sigp, (unsigned)(t + 1), __ATOMIC_RELAXED, __HIP_MEMORY_SCOPE_AGENT);
  }
}

__global__ void __launch_bounds__(256, 2)
lstm_main(const float* __restrict__ b0, const float* __restrict__ b1,
          const u16* __restrict__ W0p, const u16* __restrict__ W1p,
          const u16* __restrict__ X, u16* __restrict__ H0,
          u16* __restrict__ H1, unsigned* __restrict__ fL0,
          unsigned* __restrict__ fL1) {
  __shared__ float rbuf[8192];   // 32 KB raw-accumulator exchange
  const int tid = threadIdx.x, lane = tid & 63, w = tid >> 6;
  // R10 spread mapping (fastest measured): bands spread across XCDs so each
  // band's per-step H burst uses all 8 fabric ports; CU pair (c, c+256) = L0+L1.
  const int blk = blockIdx.x;
  const bool Lh = blk >= 256;
  const int sub = blk & 255;
  const int band = sub >> 5;
  const int ub = sub & 31;
  unsigned* fL0b = fL0 + band * 32;
  unsigned* fL1b = fL1 + band * 32;
  if (Lh)
    run_layer<true, 16, 64, 0>(band, ub, w, lane, tid, W1p, X, H0, H1, b1, fL0b, fL1b, rbuf);
  else if (w == 0)
    run_layer<false, 10, 40, 8>(band, ub, w, lane, tid, W0p, X, H0, H1, b0, fL0b, fL1b, rbuf);
  else
    run_layer<false, 10, 40, 0>(band, ub, w, lane, tid, W0p, X, H0, H1, b0, fL0b, fL1b, rbuf);
}

// ---------------- final dense (affine collapse) + sigmoid ----------------

__global__ void dense_out(const u16* __restrict__ H1f, const float* __restrict__ wd1,
                          const float* __restrict__ bd1, const float* __restrict__ wd2,
                          const float* __restrict__ bd2, float* __restrict__ out) {
  __shared__ float wv[512];
  __shared__ float beff;
  const int t = threadIdx.x;  // 512 threads
  {
    float s = 0.f;
#pragma unroll 4
    for (int j = 0; j < 32; ++j) s += wd1[t * 32 + j] * wd2[j];
    wv[t] = s;
  }
  if (t == 0) {
    float sb = 0.f;
    for (int j = 0; j < 32; ++j) sb += bd1[j] * wd2[j];
    beff = sb + bd2[0];
  }
  __syncthreads();
  if (t < 250) {
    const u16* hr = H1f + (size_t)t * 512;
    float acc = 0.f;
    for (int u = 0; u < 512; u += 8) {
      s8v hv = *(const s8v*)&hr[u];
#pragma unroll
      for (int j = 0; j < 8; ++j) acc += bf2f((u16)hv[j]) * wv[u + j];
    }
    out[t] = sigf(acc + beff);
  }
}

// ---------------- host ----------------

extern "C" void kernel_launch(void* const* d_in, const int* in_sizes, int n_in,
                              void* d_out, int out_size, void* d_ws, size_t ws_size,
                              hipStream_t stream) {
  const int*   tokens = (const int*)  d_in[0];
  const float* emb    = (const float*)d_in[1];
  const float* k0     = (const float*)d_in[2];
  const float* r0     = (const float*)d_in[3];
  const float* b0     = (const float*)d_in[4];
  const float* k1     = (const float*)d_in[5];
  const float* r1     = (const float*)d_in[6];
  const float* b1     = (const float*)d_in[7];
  const float* wd1    = (const float*)d_in[8];
  const float* bd1    = (const float*)d_in[9];
  const float* wd2    = (const float*)d_in[10];
  const float* bd2    = (const float*)d_in[11];
  float* out = (float*)d_out;

  char* ws = (char*)d_ws;
  // layout: fL0[8][32] @0 ; fL1 @2048 ; H0 ring 8x256KB @8192 ; H1 ring 8x256KB ;
  //         X 12.5MB ; W0p 2.5MB ; W1p 4MB
  unsigned* fL0 = (unsigned*)ws;
  unsigned* fL1 = (unsigned*)(ws + 2048);
  u16* H0  = (u16*)(ws + 8192);
  u16* H1  = (u16*)(ws + 8192 + 2097152);
  u16* X   = (u16*)(ws + 8192 + 4194304);
  u16* W0p = (u16*)(ws + 8192 + 4194304 + 13107200);
  u16* W1p = (u16*)(ws + 8192 + 4194304 + 13107200 + 2621440);

  zero_ws<<<4104, 256, 0, stream>>>((uint32_t*)ws, 1050624);     // flags + H rings
  gather_x<<<3200, 256, 0, stream>>>(tokens, emb, X);
  pack_wB<<<640,  256, 0, stream>>>(k0, r0, W0p, 40, 128, 100);  // L0: K=128(pad)+512
  pack_wB<<<1024, 256, 0, stream>>>(k1, r1, W1p, 64, 512, 512);  // L1: K=512+512

  void* args[] = {(void*)&b0, (void*)&b1, (void*)&W0p, (void*)&W1p,
                  (void*)&X,  (void*)&H0, (void*)&H1, (void*)&fL0, (void*)&fL1};
  (void)hipLaunchCooperativeKernel(reinterpret_cast<void*>(lstm_main),
                                   dim3(512), dim3(256), args, 0, stream);

  dense_out<<<1, 512, 0, stream>>>(H1 + (size_t)7 * HSLOT, wd1, bd1, wd2, bd2, out);
}